// Round 5
// baseline (1807.136 us; speedup 1.0000x reference)
//
#include <hip/hip_runtime.h>
#include <hip/hip_bf16.h>
#include <math.h>

typedef unsigned int u32;
typedef unsigned long long u64;

#define STRIDE 262656          // per-column stride in floats (>= max column length 262242)
#define KSHIFT 14
#define KROUND 0x2000u
#define BAND   12288           // 24 exponents x 512 mantissa steps per sign
#define NB     24576           // total bins per column (2 bands)
#define PA18   0xE200u         // (f2k(65535.97) >> 14): positive band base
#define NA18   0x2EE00u        // (f2k(-2^-8)   >> 14): negative band base
#define NCOLS  16
#define ZW4    (NB*NCOLS/4)    // uint4 words to zero a bin buffer
#define ACT_PRELU 0
#define ACT_RELU  1
#define ACT_ELU   2

__device__ __forceinline__ float k2f(u32 k){
    u32 u = (k & 0x80000000u) ? k : (k ^ 0x7FFFFFFFu);
    return __uint_as_float(u);
}

// monotone 18-bit quantization: bin 0 = largest float, NB-1 = most negative
__device__ __forceinline__ int bin_of(float v){
    float av = fabsf(v);
    av = fminf(fmaxf(av, 0.00390625f), 65535.96875f);
    u32 u = __float_as_uint(av);
    if (v < 0.f){
        u32 k = 0x80000000u | u;
        int b = (int)(((k + KROUND) >> KSHIFT) - NA18);
        b = b < 0 ? 0 : (b > BAND-1 ? BAND-1 : b);
        return BAND + b;
    } else {
        u32 k = u ^ 0x7FFFFFFFu;
        int b = (int)(((k + KROUND) >> KSHIFT) - PA18);
        b = b < 0 ? 0 : (b > BAND-1 ? BAND-1 : b);
        return b;
    }
}
__device__ __forceinline__ float bin_val(int bin){
    u32 k18 = (bin < BAND) ? ((u32)bin + PA18) : ((u32)(bin - BAND) + NA18);
    return k2f(k18 << KSHIFT);
}

// wave run-length-dedup'd histogram add (sorted-ish input -> long runs)
__device__ __forceinline__ void hist_add(u32* __restrict__ Hc, int bin, bool valid, int lane){
    u32 bn = valid ? (u32)bin : 0xFFFFFFFFu;
    u32 prev = __shfl_up(bn, 1);
    bool diff = (lane == 0) || (prev != bn);
    u64 m = __ballot(diff || !valid);
    if (valid && diff){
        u64 above = m & ~((2ull << lane) - 1ull);
        int nxt = above ? (__ffsll((unsigned long long)above) - 1) : 64;
        atomicAdd(&Hc[bin], (u32)(nxt - lane));
    }
}

// ---------------- layer-0 conv+hist with LDS-private packed-u16 histogram ----------------
// x is RANDOM -> run-dedup useless -> privatize. One output column (o,wp) per block.
#define CH0TILES 205           // 5 blocks x 205*256 = 262400 >= 262242; per-block elems 52480 < 65536
__global__ __launch_bounds__(256) void conv0_lds(const float* __restrict__ x, u32* __restrict__ H,
                                                 const float* __restrict__ w0, const float* __restrict__ b0)
{
    __shared__ u32 hist[NB/2];       // 48 KB: two u16 bins per word
    __shared__ float s0[354];
    __shared__ float sw[99];
    const int colv = blockIdx.y;     // 0..15 = o*8 + wp
    const int o = colv >> 3, wp = colv & 7;
    const int tid = threadIdx.x;
    for (int i = tid; i < NB/2; i += 256) hist[i] = 0;
    if (tid < 99) sw[tid] = w0[o*99 + tid];
    const float bias = 2.f * b0[o];  // fold doubles bias
    const int c0 = blockIdx.x * (CH0TILES*256);
    for (int t = 0; t < CH0TILES; t++){
        int h0 = c0 + t*256;
        __syncthreads();             // protect s0 from previous tile's readers
        for (int i = tid; i < 354; i += 256){
            int h = h0 - 98 + i;
            float v = 0.f;
            if (h >= 0 && h < 262144) v = x[(size_t)h*16 + 2*wp] + x[(size_t)h*16 + 2*wp + 1];
            s0[i] = v;
        }
        __syncthreads();
        int hp = h0 + tid;
        if (hp < 262242){
            float a = bias;
            for (int j = 0; j < 99; j++) a += sw[j] * s0[tid + j];
            int b = bin_of(a);
            atomicAdd(&hist[b >> 1], 1u << ((b & 1) * 16));
        }
    }
    __syncthreads();
    u32* Hc = H + (size_t)colv * NB;
    for (int i = tid; i < NB/2; i += 256){
        u32 w = hist[i];
        u32 lo = w & 0xFFFFu, hi = w >> 16;
        if (lo) atomicAdd(&Hc[2*i],   lo);
        if (hi) atomicAdd(&Hc[2*i+1], hi);
    }
}

// ---------------- generic fused conv+hist along H (sorted input -> dedup effective) ----------------
template<int INC, int OUTC>
__global__ __launch_bounds__(256) void conv_hist_t(
    const float* __restrict__ In, u32* __restrict__ H,
    const float* __restrict__ Wt, const float* __restrict__ Bs,
    int Hin, int Hout, int K, int pad, int Wi, int Wo, int foldIn, float bscale)
{
    __shared__ float sIn[INC][613];
    __shared__ float sW[OUTC*INC*358];
    const int wp = blockIdx.y;
    const int h0 = blockIdx.x * 256;
    const int tid = threadIdx.x;
    const int lane = tid & 63;
    const int tl = 256 + K - 1;
    for (int t = tid; t < INC*tl; t += 256){
        int c = t / tl, r = t - c*tl;
        int h = h0 - pad + r;
        float v = 0.f;
        if (h >= 0 && h < Hin){
            if (foldIn) v = In[(size_t)(c*Wi + 2*wp)*STRIDE + h] + In[(size_t)(c*Wi + 2*wp + 1)*STRIDE + h];
            else        v = In[(size_t)(c*Wi + wp)*STRIDE + h];
        }
        sIn[c][r] = v;
    }
    for (int t = tid; t < OUTC*INC*K; t += 256) sW[t] = Wt[t];
    __syncthreads();
    int hp = h0 + tid;
    bool valid = (hp < Hout);
    float acc[OUTC];
    #pragma unroll
    for (int o = 0; o < OUTC; o++) acc[o] = bscale * Bs[o];
    for (int c = 0; c < INC; c++){
        for (int j = 0; j < K; j++){
            float xv = sIn[c][tid + j];
            #pragma unroll
            for (int o = 0; o < OUTC; o++) acc[o] += sW[(o*INC + c)*K + j] * xv;
        }
    }
    #pragma unroll
    for (int o = 0; o < OUTC; o++)
        hist_add(H + (size_t)(o*Wo + wp)*NB, bin_of(acc[o]), valid, lane);
}

// ---------------- fused scan + reconstruct + next-bin zeroing ----------------
// grid (S, cols): each block loads counts into LDS, scans in-block, fills its rank slice.
__global__ __launch_bounds__(1024) void scan_fill(
    const u32* __restrict__ H, float* __restrict__ dst, const float* __restrict__ alphaPtr,
    int kOut, int dup, int act, uint4* __restrict__ zb)
{
    __shared__ u32 pre[NB];          // 96 KB inclusive prefix
    __shared__ u32 red[1024];
    const int col = blockIdx.y;
    const int tid = threadIdx.x;
    const u32* Hc = H + (size_t)col * NB;
    for (int i = tid; i < NB; i += 1024) pre[i] = Hc[i];
    __syncthreads();
    const int base = tid * 24;
    u32 v[24]; u32 s = 0;
    #pragma unroll
    for (int i = 0; i < 24; i++){ v[i] = pre[base + i]; s += v[i]; v[i] = s; }
    red[tid] = s;
    __syncthreads();
    for (int ofs = 1; ofs < 1024; ofs <<= 1){
        u32 t = (tid >= ofs) ? red[tid - ofs] : 0u;
        __syncthreads();
        red[tid] += t;
        __syncthreads();
    }
    u32 excl = red[tid] - s;
    #pragma unroll
    for (int i = 0; i < 24; i++) pre[base + i] = v[i] + excl;
    __syncthreads();

    const int S  = gridDim.x;
    const int nr = kOut / dup;
    const int per = (nr + S*1024 - 1) / (S*1024);
    int i = (blockIdx.x*1024 + tid) * per;
    const int i1 = min(i + per, nr);
    float* d = dst + (size_t)col * STRIDE;
    const float alpha = alphaPtr[0];
    while (i < i1){
        int lo = 0, hi = NB - 1;                  // smallest b with pre[b] > i
        while (lo < hi){ int m = (lo + hi) >> 1; if (pre[m] > (u32)i) hi = m; else lo = m + 1; }
        float vv = bin_val(lo);
        if (act == ACT_PRELU)      vv = (vv >= 0.f) ? vv : alpha * vv;
        else if (act == ACT_RELU)  vv = (vv > 0.f) ? vv : 0.f;
        else                       vv = (vv > 0.f) ? vv : expm1f(vv);
        int e = (int)min((u32)i1, pre[lo]);
        for (; i < e; i++){
            int bse = i * dup;
            for (int dd = 0; dd < dup; dd++) d[bse + dd] = vv;
        }
    }
    // zero the other bin buffer for the next layer
    const uint4 z = make_uint4(0,0,0,0);
    int lin = (blockIdx.y * gridDim.x + blockIdx.x) * 1024 + tid;
    int tot = gridDim.x * gridDim.y * 1024;
    for (int q = lin; q < ZW4; q += tot) zb[q] = z;
}

__global__ __launch_bounds__(256) void hzero(uint4* __restrict__ zb)
{
    const uint4 z = make_uint4(0,0,0,0);
    int lin = blockIdx.x * 256 + threadIdx.x;
    int tot = gridDim.x * 256;
    for (int i = lin; i < ZW4; i += tot) zb[i] = z;
}

// ---------------- FC: 1000 logits, one block each; then log_softmax ----------------
__global__ __launch_bounds__(256) void fc_dot(const float* __restrict__ A, const float* __restrict__ Wfc,
                                              const float* __restrict__ bfc, float* __restrict__ logits)
{
    const int t = blockIdx.x;            // 0..999
    const int o = t / 200, j = t - o*200;
    const float* wrow = Wfc + (size_t)j*1600;
    float acc = 0.f;
    for (int q = threadIdx.x; q < 1600; q += 256){
        int p = q >> 1, wq = q & 1;
        acc += wrow[q] * A[(size_t)(o*2 + wq)*STRIDE + p];
    }
    __shared__ float red[256];
    red[threadIdx.x] = acc;
    __syncthreads();
    for (int s = 128; s > 0; s >>= 1){
        if (threadIdx.x < s) red[threadIdx.x] += red[threadIdx.x + s];
        __syncthreads();
    }
    if (threadIdx.x == 0) logits[t] = red[0] + bfc[j];
}

__global__ __launch_bounds__(1024) void lsm(const float* __restrict__ logits, float* __restrict__ out)
{
    const int tid = threadIdx.x;
    __shared__ float red[1024];
    float lg = (tid < 1000) ? logits[tid] : -INFINITY;
    red[tid] = lg;
    __syncthreads();
    for (int s = 512; s > 0; s >>= 1){
        if (tid < s) red[tid] = fmaxf(red[tid], red[tid + s]);
        __syncthreads();
    }
    float m = red[0];
    __syncthreads();
    red[tid] = (tid < 1000) ? expf(lg - m) : 0.f;
    __syncthreads();
    for (int s = 512; s > 0; s >>= 1){
        if (tid < s) red[tid] += red[tid + s];
        __syncthreads();
    }
    float lse = logf(red[0]);
    if (tid < 1000) out[tid] = lg - m - lse;
}

extern "C" void kernel_launch(void* const* d_in, const int* in_sizes, int n_in,
                              void* d_out, int out_size, void* d_ws, size_t ws_size,
                              hipStream_t stream)
{
    (void)in_sizes; (void)n_in; (void)out_size;
    const size_t need = (size_t)16*STRIDE*4 + (size_t)2*NB*NCOLS*4 + 4096;
    if (ws_size < need) return;

    const float* x   = (const float*)d_in[0];
    const float* w0  = (const float*)d_in[1];
    const float* b0  = (const float*)d_in[2];
    const float* wm  = (const float*)d_in[3];
    const float* bm  = (const float*)d_in[4];
    const float* w18 = (const float*)d_in[5];
    const float* b18 = (const float*)d_in[6];
    const float* w19 = (const float*)d_in[7];
    const float* b19 = (const float*)d_in[8];
    const float* a1  = (const float*)d_in[9];
    const float* a2  = (const float*)d_in[10];
    const float* Wfc = (const float*)d_in[11];
    const float* bfc = (const float*)d_in[12];

    float* b1   = (float*)d_ws;
    u32*  bin0  = (u32*)(b1 + (size_t)16*STRIDE);
    u32*  bin1  = bin0 + (size_t)NB*NCOLS;
    float* logits = (float*)(bin1 + (size_t)NB*NCOLS);

    u32* cur = bin0;
    u32* nxt = bin1;

    hzero<<<384, 256, 0, stream>>>((uint4*)cur);

    // ---- layer 0: conv(99, pad 98) -> fold(x2 dup) -> kmax 262144 -> PReLU(a1) ----
    conv0_lds<<<dim3(5, 16), 256, 0, stream>>>(x, cur, w0, b0);
    scan_fill<<<dim3(8, 16), 1024, 0, stream>>>(cur, b1, a1, 262144, 2, ACT_PRELU, (uint4*)nxt);
    { u32* t = cur; cur = nxt; nxt = t; }
    int Hin = 262144;

    // ---- layers 1..17: conv(9, pad 8) -> kmax -> PReLU(a2)/ReLU ----
    static const int ks[17] = {249036,235929,222822,209715,196608,183500,170393,157286,
                               144179,131072,117964,104857,91750,78643,65536,52428,39321};
    for (int i = 0; i < 17; i++){
        int Hout = Hin + 8;
        conv_hist_t<2,2><<<dim3((Hout + 255)/256, 8), 256, 0, stream>>>(
            b1, cur, wm + (size_t)i*36, bm + (size_t)i*2, Hin, Hout, 9, 8, 8, 8, 0, 1.f);
        scan_fill<<<dim3(8, 16), 1024, 0, stream>>>(cur, b1, a2, ks[i], 1,
                                                    (i == 0) ? ACT_PRELU : ACT_RELU, (uint4*)nxt);
        { u32* t = cur; cur = nxt; nxt = t; }
        Hin = ks[i];
    }

    // ---- layer 18: conv(9) -> fold(widths 8->4, x2 dup) -> kmax 26214 -> ELU ----
    {
        int Hout = Hin + 8;   // 39329
        conv_hist_t<2,2><<<dim3((Hout + 255)/256, 4), 256, 0, stream>>>(
            b1, cur, w18, b18, Hin, Hout, 9, 8, 8, 4, 1, 2.f);
        scan_fill<<<dim3(2, 8), 1024, 0, stream>>>(cur, b1, a2, 26214, 2, ACT_ELU, (uint4*)nxt);
        { u32* t = cur; cur = nxt; nxt = t; }
        Hin = 26214;
    }

    // ---- layer 19: conv(358, pad 357, 2->5ch) -> fold(widths 4->2, x5 dup) -> kmax 800 -> ELU ----
    {
        int Hout = Hin + 714 - 358 + 1;   // 26571
        conv_hist_t<2,5><<<dim3((Hout + 255)/256, 2), 256, 0, stream>>>(
            b1, cur, w19, b19, Hin, Hout, 358, 357, 4, 2, 1, 2.f);
        scan_fill<<<dim3(1, 10), 1024, 0, stream>>>(cur, b1, a2, 800, 5, ACT_ELU, (uint4*)nxt);
    }

    // ---- FC + log_softmax ----
    fc_dot<<<1000, 256, 0, stream>>>(b1, Wfc, bfc, logits);
    lsm<<<1, 1024, 0, stream>>>(logits, (float*)d_out);
}

// Round 6
// 1668.948 us; speedup vs baseline: 1.0828x; 1.0828x over previous
//
#include <hip/hip_runtime.h>
#include <hip/hip_bf16.h>
#include <math.h>

typedef unsigned int u32;
typedef unsigned long long u64;

#define STRIDE 262656          // per-column stride in floats (>= max column length 262242)
#define KSHIFT 14
#define KROUND 0x2000u
#define BAND   12288           // 24 exponents x 512 mantissa steps per sign
#define NB     24576           // total bins per column (2 bands)
#define PA18   0xE200u         // (f2k(65535.97) >> 14): positive band base
#define NA18   0x2EE00u        // (f2k(-2^-8)   >> 14): negative band base
#define NCOLS  16
#define ZW4    (NB*NCOLS/4)    // uint4 words to zero a bin buffer
#define ACT_PRELU 0
#define ACT_RELU  1
#define ACT_ELU   2

__device__ __forceinline__ float k2f(u32 k){
    u32 u = (k & 0x80000000u) ? k : (k ^ 0x7FFFFFFFu);
    return __uint_as_float(u);
}

// monotone 18-bit quantization: bin 0 = largest float, NB-1 = most negative
__device__ __forceinline__ int bin_of(float v){
    float av = fabsf(v);
    av = fminf(fmaxf(av, 0.00390625f), 65535.96875f);
    u32 u = __float_as_uint(av);
    if (v < 0.f){
        u32 k = 0x80000000u | u;
        int b = (int)(((k + KROUND) >> KSHIFT) - NA18);
        b = b < 0 ? 0 : (b > BAND-1 ? BAND-1 : b);
        return BAND + b;
    } else {
        u32 k = u ^ 0x7FFFFFFFu;
        int b = (int)(((k + KROUND) >> KSHIFT) - PA18);
        b = b < 0 ? 0 : (b > BAND-1 ? BAND-1 : b);
        return b;
    }
}
__device__ __forceinline__ float bin_val(int bin){
    u32 k18 = (bin < BAND) ? ((u32)bin + PA18) : ((u32)(bin - BAND) + NA18);
    return k2f(k18 << KSHIFT);
}

// wave run-length-dedup'd histogram add (used only by layer-19 global path)
__device__ __forceinline__ void hist_add(u32* __restrict__ Hc, int bin, bool valid, int lane){
    u32 bn = valid ? (u32)bin : 0xFFFFFFFFu;
    u32 prev = __shfl_up(bn, 1);
    bool diff = (lane == 0) || (prev != bn);
    u64 m = __ballot(diff || !valid);
    if (valid && diff){
        u64 above = m & ~((2ull << lane) - 1ull);
        int nxt = above ? (__ffsll((unsigned long long)above) - 1) : 64;
        atomicAdd(&Hc[bin], (u32)(nxt - lane));
    }
}

// ---------------- fold+transpose x: [262144][16] row-major -> fx[8][STRIDE] col-major ----------------
__global__ __launch_bounds__(256) void foldx(const float* __restrict__ x, float* __restrict__ fx)
{
    __shared__ float4 tile[1024];    // 256 rows x 16 floats
    const int tid = threadIdx.x;
    const int h0 = blockIdx.x * 256;
    for (int i = tid; i < 1024; i += 256) tile[i] = ((const float4*)x)[(size_t)h0*4 + i];
    __syncthreads();
    float4 a = tile[tid*4+0], b = tile[tid*4+1], c = tile[tid*4+2], d = tile[tid*4+3];
    const int h = h0 + tid;
    fx[(size_t)0*STRIDE + h] = a.x + a.y;
    fx[(size_t)1*STRIDE + h] = a.z + a.w;
    fx[(size_t)2*STRIDE + h] = b.x + b.y;
    fx[(size_t)3*STRIDE + h] = b.z + b.w;
    fx[(size_t)4*STRIDE + h] = c.x + c.y;
    fx[(size_t)5*STRIDE + h] = c.z + c.w;
    fx[(size_t)6*STRIDE + h] = d.x + d.y;
    fx[(size_t)7*STRIDE + h] = d.z + d.w;
}

// ---------------- layer-0 conv+hist: contiguous fx input, LDS-private packed-u16 hist ----------------
#define C0CHUNK 13120            // 20 chunks x 13120 = 262400 >= 262242; < 65536 (u16 safe)
__global__ __launch_bounds__(512) void conv0_lds(const float* __restrict__ fx, u32* __restrict__ H,
                                                 const float* __restrict__ w0, const float* __restrict__ b0)
{
    __shared__ u32 hist[NB/2];       // 48 KB packed u16 pairs
    __shared__ float s0[610];
    __shared__ float sw[99];
    const int colv = blockIdx.y;     // 0..15 = o*8 + wp
    const int o = colv >> 3, wp = colv & 7;
    const int tid = threadIdx.x;
    const int p0 = blockIdx.x * C0CHUNK;
    const int p1 = min(p0 + C0CHUNK, 262242);
    for (int i = tid; i < NB/2; i += 512) hist[i] = 0;
    if (tid < 99) sw[tid] = w0[o*99 + tid];
    const float bias = 2.f * b0[o];  // fold doubles bias
    __syncthreads();
    const float* fc = fx + (size_t)wp * STRIDE;
    for (int t0 = p0; t0 < p1; t0 += 512){
        for (int i = tid; i < 610; i += 512){
            int h = t0 - 98 + i;
            s0[i] = (h >= 0 && h < 262144) ? fc[h] : 0.f;
        }
        __syncthreads();
        int hp = t0 + tid;
        if (hp < p1){
            float a = bias;
            #pragma unroll
            for (int j = 0; j < 99; j++) a += sw[j] * s0[tid + j];
            int b = bin_of(a);
            atomicAdd(&hist[b >> 1], 1u << ((b & 1) * 16));
        }
        __syncthreads();
    }
    u32* Hc = H + (size_t)colv * NB;
    for (int i = tid; i < NB/2; i += 512){
        u32 w = hist[i];
        if (w){
            u32 lo = w & 0xFFFFu, hi = w >> 16;
            if (lo) atomicAdd(&Hc[2*i],   lo);
            if (hi) atomicAdd(&Hc[2*i+1], hi);
        }
    }
}

// ---------------- K=9 conv+hist, LDS-private hists for BOTH output channels ----------------
#define C9CHUNK 13056            // < 65536 (u16 safe), multiple of 512
template<int FOLDIN>
__global__ __launch_bounds__(512) void conv9_lds(
    const float* __restrict__ In, u32* __restrict__ H,
    const float* __restrict__ Wt, const float* __restrict__ Bs,
    int Hin, int Hout, int Wi, int Wo, float bscale)
{
    __shared__ u32 hh[2][NB/2];      // 96 KB
    __shared__ float s[2][520];
    __shared__ float sw[36];
    const int wp = blockIdx.y;
    const int tid = threadIdx.x;
    const int p0 = blockIdx.x * C9CHUNK;
    const int p1 = min(p0 + C9CHUNK, Hout);
    for (int i = tid; i < NB/2; i += 512){ hh[0][i] = 0; hh[1][i] = 0; }
    if (tid < 36) sw[tid] = Wt[tid];
    const float bv0 = bscale * Bs[0], bv1 = bscale * Bs[1];
    __syncthreads();
    for (int t0 = p0; t0 < p1; t0 += 512){
        for (int i = tid; i < 2*520; i += 512){
            int c = i / 520, r = i - c*520;
            int h = t0 - 8 + r;
            float v = 0.f;
            if (h >= 0 && h < Hin){
                if (FOLDIN) v = In[(size_t)(c*Wi + 2*wp)*STRIDE + h] + In[(size_t)(c*Wi + 2*wp + 1)*STRIDE + h];
                else        v = In[(size_t)(c*Wi + wp)*STRIDE + h];
            }
            s[c][r] = v;
        }
        __syncthreads();
        int hp = t0 + tid;
        if (hp < p1){
            float a0 = bv0, a1 = bv1;
            #pragma unroll
            for (int c = 0; c < 2; c++)
                #pragma unroll
                for (int j = 0; j < 9; j++){
                    float xv = s[c][tid + j];
                    a0 += sw[(0*2 + c)*9 + j] * xv;
                    a1 += sw[(1*2 + c)*9 + j] * xv;
                }
            int q0 = bin_of(a0), q1 = bin_of(a1);
            atomicAdd(&hh[0][q0 >> 1], 1u << ((q0 & 1) * 16));
            atomicAdd(&hh[1][q1 >> 1], 1u << ((q1 & 1) * 16));
        }
        __syncthreads();
    }
    u32* H0 = H + (size_t)(0*Wo + wp)*NB;
    u32* H1 = H + (size_t)(1*Wo + wp)*NB;
    for (int i = tid; i < NB/2; i += 512){
        u32 w0_ = hh[0][i];
        if (w0_){
            u32 lo = w0_ & 0xFFFFu, hi = w0_ >> 16;
            if (lo) atomicAdd(&H0[2*i],   lo);
            if (hi) atomicAdd(&H0[2*i+1], hi);
        }
        u32 w1_ = hh[1][i];
        if (w1_){
            u32 lo = w1_ & 0xFFFFu, hi = w1_ >> 16;
            if (lo) atomicAdd(&H1[2*i],   lo);
            if (hi) atomicAdd(&H1[2*i+1], hi);
        }
    }
}

// ---------------- layer-19 conv+hist (small; global atomics with run dedup) ----------------
template<int INC, int OUTC>
__global__ __launch_bounds__(256) void conv_hist_t(
    const float* __restrict__ In, u32* __restrict__ H,
    const float* __restrict__ Wt, const float* __restrict__ Bs,
    int Hin, int Hout, int K, int pad, int Wi, int Wo, int foldIn, float bscale)
{
    __shared__ float sIn[INC][613];
    __shared__ float sW[OUTC*INC*358];
    const int wp = blockIdx.y;
    const int h0 = blockIdx.x * 256;
    const int tid = threadIdx.x;
    const int lane = tid & 63;
    const int tl = 256 + K - 1;
    for (int t = tid; t < INC*tl; t += 256){
        int c = t / tl, r = t - c*tl;
        int h = h0 - pad + r;
        float v = 0.f;
        if (h >= 0 && h < Hin){
            if (foldIn) v = In[(size_t)(c*Wi + 2*wp)*STRIDE + h] + In[(size_t)(c*Wi + 2*wp + 1)*STRIDE + h];
            else        v = In[(size_t)(c*Wi + wp)*STRIDE + h];
        }
        sIn[c][r] = v;
    }
    for (int t = tid; t < OUTC*INC*K; t += 256) sW[t] = Wt[t];
    __syncthreads();
    int hp = h0 + tid;
    bool valid = (hp < Hout);
    float acc[OUTC];
    #pragma unroll
    for (int o = 0; o < OUTC; o++) acc[o] = bscale * Bs[o];
    for (int c = 0; c < INC; c++){
        for (int j = 0; j < K; j++){
            float xv = sIn[c][tid + j];
            #pragma unroll
            for (int o = 0; o < OUTC; o++) acc[o] += sW[(o*INC + c)*K + j] * xv;
        }
    }
    #pragma unroll
    for (int o = 0; o < OUTC; o++)
        hist_add(H + (size_t)(o*Wo + wp)*NB, bin_of(acc[o]), valid, lane);
}

// ---------------- fused scan + reconstruct + next-bin zeroing ----------------
__global__ __launch_bounds__(1024) void scan_fill(
    const u32* __restrict__ H, float* __restrict__ dst, const float* __restrict__ alphaPtr,
    int kOut, int dup, int act, uint4* __restrict__ zb)
{
    __shared__ u32 pre[NB];          // 96 KB inclusive prefix
    __shared__ u32 warr[16];
    const int col = blockIdx.y;
    const int tid = threadIdx.x;
    const int lane = tid & 63, wv = tid >> 6;
    const u32* Hc = H + (size_t)col * NB;
    for (int i = tid; i < NB; i += 1024) pre[i] = Hc[i];
    __syncthreads();
    const int base = tid * 24;
    u32 v[24]; u32 s = 0;
    #pragma unroll
    for (int i = 0; i < 24; i++){ v[i] = pre[base + i]; s += v[i]; v[i] = s; }
    u32 ss = s;
    #pragma unroll
    for (int d = 1; d < 64; d <<= 1){
        u32 t = __shfl_up(ss, d);
        if (lane >= d) ss += t;
    }
    if (lane == 63) warr[wv] = ss;
    __syncthreads();
    u32 wb = 0;
    #pragma unroll
    for (int w = 0; w < 16; w++) wb += (w < wv) ? warr[w] : 0u;
    u32 excl = wb + ss - s;
    #pragma unroll
    for (int i = 0; i < 24; i++) pre[base + i] = v[i] + excl;
    __syncthreads();

    const int S  = gridDim.x;
    const int nr = kOut / dup;
    const int per = (nr + S*1024 - 1) / (S*1024);
    int i = (blockIdx.x*1024 + tid) * per;
    const int i1 = min(i + per, nr);
    float* d = dst + (size_t)col * STRIDE;
    const float alpha = alphaPtr[0];
    while (i < i1){
        int lo = 0, hi = NB - 1;                  // smallest b with pre[b] > i
        while (lo < hi){ int m = (lo + hi) >> 1; if (pre[m] > (u32)i) hi = m; else lo = m + 1; }
        float vv = bin_val(lo);
        if (act == ACT_PRELU)      vv = (vv >= 0.f) ? vv : alpha * vv;
        else if (act == ACT_RELU)  vv = (vv > 0.f) ? vv : 0.f;
        else                       vv = (vv > 0.f) ? vv : expm1f(vv);
        int e = (int)min((u32)i1, pre[lo]);
        for (; i < e; i++){
            int bse = i * dup;
            for (int dd = 0; dd < dup; dd++) d[bse + dd] = vv;
        }
    }
    // zero the other bin buffer for the next layer
    const uint4 z = make_uint4(0,0,0,0);
    int lin = (blockIdx.y * gridDim.x + blockIdx.x) * 1024 + tid;
    int tot = gridDim.x * gridDim.y * 1024;
    for (int q = lin; q < ZW4; q += tot) zb[q] = z;
}

__global__ __launch_bounds__(256) void hzero(uint4* __restrict__ zb)
{
    const uint4 z = make_uint4(0,0,0,0);
    int lin = blockIdx.x * 256 + threadIdx.x;
    int tot = gridDim.x * 256;
    for (int i = lin; i < ZW4; i += tot) zb[i] = z;
}

// ---------------- FC: 1000 logits, one block each; then log_softmax ----------------
__global__ __launch_bounds__(256) void fc_dot(const float* __restrict__ A, const float* __restrict__ Wfc,
                                              const float* __restrict__ bfc, float* __restrict__ logits)
{
    const int t = blockIdx.x;            // 0..999
    const int o = t / 200, j = t - o*200;
    const float* wrow = Wfc + (size_t)j*1600;
    float acc = 0.f;
    for (int q = threadIdx.x; q < 1600; q += 256){
        int p = q >> 1, wq = q & 1;
        acc += wrow[q] * A[(size_t)(o*2 + wq)*STRIDE + p];
    }
    __shared__ float red[256];
    red[threadIdx.x] = acc;
    __syncthreads();
    for (int s = 128; s > 0; s >>= 1){
        if (threadIdx.x < s) red[threadIdx.x] += red[threadIdx.x + s];
        __syncthreads();
    }
    if (threadIdx.x == 0) logits[t] = red[0] + bfc[j];
}

__global__ __launch_bounds__(1024) void lsm(const float* __restrict__ logits, float* __restrict__ out)
{
    const int tid = threadIdx.x;
    __shared__ float red[1024];
    float lg = (tid < 1000) ? logits[tid] : -INFINITY;
    red[tid] = lg;
    __syncthreads();
    for (int s = 512; s > 0; s >>= 1){
        if (tid < s) red[tid] = fmaxf(red[tid], red[tid + s]);
        __syncthreads();
    }
    float m = red[0];
    __syncthreads();
    red[tid] = (tid < 1000) ? expf(lg - m) : 0.f;
    __syncthreads();
    for (int s = 512; s > 0; s >>= 1){
        if (tid < s) red[tid] += red[tid + s];
        __syncthreads();
    }
    float lse = logf(red[0]);
    if (tid < 1000) out[tid] = lg - m - lse;
}

extern "C" void kernel_launch(void* const* d_in, const int* in_sizes, int n_in,
                              void* d_out, int out_size, void* d_ws, size_t ws_size,
                              hipStream_t stream)
{
    (void)in_sizes; (void)n_in; (void)out_size;
    const size_t need = (size_t)24*STRIDE*4 + (size_t)2*NB*NCOLS*4 + 4096;
    if (ws_size < need) return;

    const float* x   = (const float*)d_in[0];
    const float* w0  = (const float*)d_in[1];
    const float* b0  = (const float*)d_in[2];
    const float* wm  = (const float*)d_in[3];
    const float* bm  = (const float*)d_in[4];
    const float* w18 = (const float*)d_in[5];
    const float* b18 = (const float*)d_in[6];
    const float* w19 = (const float*)d_in[7];
    const float* b19 = (const float*)d_in[8];
    const float* a1  = (const float*)d_in[9];
    const float* a2  = (const float*)d_in[10];
    const float* Wfc = (const float*)d_in[11];
    const float* bfc = (const float*)d_in[12];

    float* b1   = (float*)d_ws;
    float* fx   = b1 + (size_t)16*STRIDE;
    u32*  bin0  = (u32*)(fx + (size_t)8*STRIDE);
    u32*  bin1  = bin0 + (size_t)NB*NCOLS;
    float* logits = (float*)(bin1 + (size_t)NB*NCOLS);

    u32* cur = bin0;
    u32* nxt = bin1;

    foldx<<<1024, 256, 0, stream>>>(x, fx);
    hzero<<<384, 256, 0, stream>>>((uint4*)cur);

    // ---- layer 0: conv(99, pad 98) -> fold(x2 dup) -> kmax 262144 -> PReLU(a1) ----
    conv0_lds<<<dim3(20, 16), 512, 0, stream>>>(fx, cur, w0, b0);
    scan_fill<<<dim3(8, 16), 1024, 0, stream>>>(cur, b1, a1, 262144, 2, ACT_PRELU, (uint4*)nxt);
    { u32* t = cur; cur = nxt; nxt = t; }
    int Hin = 262144;

    // ---- layers 1..17: conv(9, pad 8) -> kmax -> PReLU(a2)/ReLU ----
    static const int ks[17] = {249036,235929,222822,209715,196608,183500,170393,157286,
                               144179,131072,117964,104857,91750,78643,65536,52428,39321};
    for (int i = 0; i < 17; i++){
        int Hout = Hin + 8;
        int nch = (Hout + C9CHUNK - 1) / C9CHUNK;
        conv9_lds<0><<<dim3(nch, 8), 512, 0, stream>>>(
            b1, cur, wm + (size_t)i*36, bm + (size_t)i*2, Hin, Hout, 8, 8, 1.f);
        scan_fill<<<dim3(8, 16), 1024, 0, stream>>>(cur, b1, a2, ks[i], 1,
                                                    (i == 0) ? ACT_PRELU : ACT_RELU, (uint4*)nxt);
        { u32* t = cur; cur = nxt; nxt = t; }
        Hin = ks[i];
    }

    // ---- layer 18: conv(9) -> fold(widths 8->4, x2 dup) -> kmax 26214 -> ELU ----
    {
        int Hout = Hin + 8;   // 39329
        int nch = (Hout + C9CHUNK - 1) / C9CHUNK;
        conv9_lds<1><<<dim3(nch, 4), 512, 0, stream>>>(
            b1, cur, w18, b18, Hin, Hout, 8, 4, 2.f);
        scan_fill<<<dim3(2, 8), 1024, 0, stream>>>(cur, b1, a2, 26214, 2, ACT_ELU, (uint4*)nxt);
        { u32* t = cur; cur = nxt; nxt = t; }
        Hin = 26214;
    }

    // ---- layer 19: conv(358, pad 357, 2->5ch) -> fold(widths 4->2, x5 dup) -> kmax 800 -> ELU ----
    {
        int Hout = Hin + 714 - 358 + 1;   // 26571
        conv_hist_t<2,5><<<dim3((Hout + 255)/256, 2), 256, 0, stream>>>(
            b1, cur, w19, b19, Hin, Hout, 358, 357, 4, 2, 1, 2.f);
        scan_fill<<<dim3(1, 10), 1024, 0, stream>>>(cur, b1, a2, 800, 5, ACT_ELU, (uint4*)nxt);
    }

    // ---- FC + log_softmax ----
    fc_dot<<<1000, 256, 0, stream>>>(b1, Wfc, bfc, logits);
    lsm<<<1, 1024, 0, stream>>>(logits, (float*)d_out);
}